// Round 4
// baseline (6427.582 us; speedup 1.0000x reference)
//
#include <hip/hip_runtime.h>
#include <cstdint>

#define BATCH 64
#define SEQ   512
#define DIN   862
#define DPAD  896
#define HID   1024
#define NG    4096
#define POIS  0xFFFFFFFFu   // f16 NaN pair: |h|<=1 can never produce this pattern

typedef _Float16 f16;
typedef __attribute__((ext_vector_type(8))) _Float16 f16x8;
typedef __attribute__((ext_vector_type(4))) float    f32x4;
typedef unsigned long long u64;

// ---------------- async global->LDS (16B per lane, wave-uniform LDS base) -------------
__device__ __forceinline__ void glds16(const f16* g, f16* l) {
    auto gp = (const __attribute__((address_space(1))) void*)(uintptr_t)g;
    auto lp = (__attribute__((address_space(3))) void*)(uint32_t)(uintptr_t)l;
    __builtin_amdgcn_global_load_lds(gp, lp, 16, 0, 0);
}

__device__ __forceinline__ float sigf(float x) {
    return __builtin_amdgcn_rcpf(1.f + __expf(-x));
}
__device__ __forceinline__ float tanh_fast(float x) {
    float xx = fminf(15.f, fmaxf(-15.f, x));
    float e = __expf(2.f * xx);
    return (e - 1.f) * __builtin_amdgcn_rcpf(e + 1.f);
}

// XG layout: [t][bs(4)][jg(64)][g(4)][bl(16)][jl(16)]  (f16, bias included)
__device__ __forceinline__ long xg_index(int t, int b, int n) {
    int bs = b >> 4, bl = b & 15;
    int g = n >> 10, jh = n & 1023;
    int jg = jh >> 4, jl = jh & 15;
    return (((((long)t * 4 + bs) * 64 + jg) * 4 + g) * 16 + bl) * 16 + jl;
}

// ---------------- prep: conversions, padding, bias sums, h-buffer poisoning -----------
__global__ __launch_bounds__(256) void prep_kernel(
    const float* __restrict__ x,
    const float* __restrict__ Wih0, const float* __restrict__ Whh0,
    const float* __restrict__ bih0, const float* __restrict__ bhh0,
    const float* __restrict__ Wih1, const float* __restrict__ Whh1,
    const float* __restrict__ bih1, const float* __restrict__ bhh1,
    f16* __restrict__ xh, f16* __restrict__ W0h, f16* __restrict__ Wh0h,
    f16* __restrict__ W1h, f16* __restrict__ Wh1h,
    float* __restrict__ b0, float* __restrict__ b1,
    unsigned* __restrict__ h1p, unsigned* __restrict__ h2p)
{
    long tid = (long)blockIdx.x * blockDim.x + threadIdx.x;
    long np  = (long)gridDim.x * blockDim.x;
    for (long i = tid; i < (long)BATCH * SEQ * DPAD; i += np) {
        long m = i / DPAD, k = i % DPAD;
        xh[i] = (k < DIN) ? (f16)x[m * DIN + k] : (f16)0.f;
    }
    for (long i = tid; i < (long)NG * DPAD; i += np) {
        long n = i / DPAD, k = i % DPAD;
        W0h[i] = (k < DIN) ? (f16)Wih0[n * DIN + k] : (f16)0.f;
    }
    for (long i = tid; i < (long)NG * HID; i += np) {
        Wh0h[i] = (f16)Whh0[i];
        W1h[i]  = (f16)Wih1[i];
        Wh1h[i] = (f16)Whh1[i];
    }
    for (long i = tid; i < NG; i += np) { b0[i] = bih0[i] + bhh0[i]; b1[i] = bih1[i] + bhh1[i]; }
    // poison both h buffers at the COHERENCE POINT (sc1 stores): data-flow sentinel.
    // Plain cached stores would leave the poison dirty in per-XCD L2 while consumers'
    // L2-bypassing loads could still read the previous launch's values from IF.
    const long HW = (long)SEQ * BATCH * HID / 2;   // u32 count
    for (long i = tid; i < HW; i += np) {
        __hip_atomic_store(&h1p[i], POIS, __ATOMIC_RELAXED, __HIP_MEMORY_SCOPE_AGENT);
        __hip_atomic_store(&h2p[i], POIS, __ATOMIC_RELAXED, __HIP_MEMORY_SCOPE_AGENT);
    }
}

// ---------------- f16 GEMM: gates[m][n] = A[m][:K] . Bw[n][:K] + bias[n] --------------
// A [32768][K], Bw [4096][K] (row-major, = W^T applied), out = XG layout (f16).
// mode 1: A rows are m = b*512 + t   (layer-1 input x)
// mode 2: A rows are m = t*64 + b    (layer-2 input h1)
__global__ __launch_bounds__(256) void gemm_f16(
    const f16* __restrict__ A, const f16* __restrict__ Bw,
    const float* __restrict__ bias, f16* __restrict__ out, int K, int mode)
{
    __shared__ f16 smem[2 * 128 * 32];   // A tile | B tile, 8KB each
    const int tid  = threadIdx.x;
    const int lane = tid & 63, wave = tid >> 6;
    const int wm = wave >> 1, wn = wave & 1;
    const int quad = lane >> 4, l15 = lane & 15;
    const int bm = blockIdx.x >> 5, bn = blockIdx.x & 31;
    const long m0 = (long)bm * 128, n0 = (long)bn * 128;
    const int r4 = lane >> 2, g4 = lane & 3;

    f32x4 acc[4][4];
#pragma unroll
    for (int i = 0; i < 4; ++i)
#pragma unroll
        for (int j = 0; j < 4; ++j)
#pragma unroll
            for (int r = 0; r < 4; ++r) acc[i][j][r] = 0.f;

#pragma unroll 1
    for (int kk = 0; kk < K; kk += 32) {
#pragma unroll
        for (int c = 0; c < 2; ++c) {
            int idx = wave * 2 + c;
            int lr  = idx * 16 + r4;
            int gs  = g4 ^ ((lr >> 1) & 3);          // XOR-swizzled source granule
            glds16(A  + (m0 + lr) * (long)K + kk + gs * 8, smem + idx * 512);
            glds16(Bw + (n0 + lr) * (long)K + kk + gs * 8, smem + 4096 + idx * 512);
        }
        __syncthreads();
        f16x8 af[4], bf[4];
#pragma unroll
        for (int i = 0; i < 4; ++i) {
            int lr = 64 * wm + 16 * i + l15;
            int sl = quad ^ ((lr >> 1) & 3);
            af[i] = *(const f16x8*)(smem + lr * 32 + sl * 8);
        }
#pragma unroll
        for (int j = 0; j < 4; ++j) {
            int lr = 64 * wn + 16 * j + l15;
            int sl = quad ^ ((lr >> 1) & 3);
            bf[j] = *(const f16x8*)(smem + 4096 + lr * 32 + sl * 8);
        }
#pragma unroll
        for (int i = 0; i < 4; ++i)
#pragma unroll
            for (int j = 0; j < 4; ++j)
                acc[i][j] = __builtin_amdgcn_mfma_f32_16x16x32_f16(af[i], bf[j], acc[i][j], 0, 0, 0);
        __syncthreads();
    }

#pragma unroll
    for (int j = 0; j < 4; ++j) {
        int n = (int)n0 + 64 * wn + 16 * j + l15;
        float bv = bias[n];
#pragma unroll
        for (int i = 0; i < 4; ++i) {
#pragma unroll
            for (int r = 0; r < 4; ++r) {
                int m = (int)m0 + 64 * wm + 16 * i + quad * 4 + r;
                int t, b;
                if (mode == 1) { b = m >> 9; t = m & 511; }
                else           { t = m >> 6; b = m & 63; }
                out[xg_index(t, b, n)] = (f16)(acc[i][j][r] + bv);
            }
        }
    }
}

// ---------------- persistent LSTM layer, pure data-flow sync --------------------------
// 256 blocks = 4 batch-slices (bs) x 64 hidden-groups (jg, 16 hidden units each).
// NO grid barrier, NO counters: h(t) slots are pre-poisoned (0xFFFFFFFF = f16 NaN pair,
// unreachable since |h|<=1); producers fire-and-forget sc1 u32 stores; consumers load
// the fragments with coherent (L2-bypassing) loads and retry while any u32 is poison.
// Handoff = one store propagation + one load: the minimum possible. bs-groups decouple.
__global__ __launch_bounds__(256, 1) void lstm_layer(
    const f16* __restrict__ xg, const f16* __restrict__ Whh,
    f16* __restrict__ hseq, float* __restrict__ out32)
{
    __shared__ float P[4 * 4 * 16 * 17];   // [src w][g][b 16][j 16+pad] = 17408 B
    const int tid = threadIdx.x;
    const int lane = tid & 63, w = tid >> 6;
    const int quad = lane >> 4, l15 = lane & 15;
    const int bs = blockIdx.x & 3;        // batch slice: batches bs*16..bs*16+15
    const int jg = blockIdx.x >> 2;       // hidden group: units jg*16..jg*16+15
    const int ks0 = 256 * w;              // this wave's K-slice

    // persistent W_hh fragments: wf[gate][kstep]; B-frag row l15 = hidden jl
    f16x8 wf[4][8];
#pragma unroll
    for (int g = 0; g < 4; ++g) {
        const f16* Wp = Whh + ((long)g * HID + jg * 16 + l15) * HID + ks0 + quad * 8;
#pragma unroll
        for (int s = 0; s < 8; ++s)
            wf[g][s] = *(const f16x8*)(Wp + s * 32);
    }
#pragma unroll
    for (int g = 0; g < 4; ++g)
#pragma unroll
        for (int s = 0; s < 8; ++s)
            asm volatile("" : "+v"(wf[g][s]));   // pin: no remat inside t-loop

    const int gb = tid >> 4, gj = tid & 15;
    const int bG = bs * 16 + gb, jG = jg * 16 + gj;
    unsigned* hw = (unsigned*)hseq;
    float cst = 0.f;

#pragma unroll 1
    for (int t = 0; t < SEQ; ++t) {
        // xg loads: independent of h, issue before the poll so latency hides under it
        const f16* xp = xg + (((long)t * 4 + bs) * 64 + jg) * 1024 + gb * 16 + gj;
        float xgi = (float)xp[0];
        float xgf = (float)xp[256];
        float xgg = (float)xp[512];
        float xgo = (float)xp[768];

        f32x4 acc[4];
#pragma unroll
        for (int g = 0; g < 4; ++g)
#pragma unroll
            for (int r = 0; r < 4; ++r) acc[g][r] = 0.f;

        if (t > 0) {
            // fragment base for this lane (f16 units); per-s stride = 32 f16 = 64 B
            const f16* hpf = hseq + ((long)(t - 1) * BATCH + bs * 16 + l15) * HID + ks0 + quad * 8;
            f16x8 af[8];
            // data-flow poll: load fragments, retry while any u32 half is poison
            for (;;) {
                bool ok = true;
#pragma unroll
                for (int s = 0; s < 8; ++s) {
                    const u64* p = (const u64*)(hpf + s * 32);
                    u64 a = __hip_atomic_load((u64*)p,
                                              __ATOMIC_RELAXED, __HIP_MEMORY_SCOPE_AGENT);
                    u64 b = __hip_atomic_load((u64*)p + 1,
                                              __ATOMIC_RELAXED, __HIP_MEMORY_SCOPE_AGENT);
                    ok = ok && ((unsigned)a != POIS) && ((unsigned)(a >> 32) != POIS)
                            && ((unsigned)b != POIS) && ((unsigned)(b >> 32) != POIS);
                    union { u64 u[2]; f16x8 v; } cv2;
                    cv2.u[0] = a; cv2.u[1] = b;
                    af[s] = cv2.v;
                }
                if (__all((int)ok)) break;
                __builtin_amdgcn_s_sleep(1);
            }
#pragma unroll
            for (int s = 0; s < 8; ++s)
#pragma unroll
                for (int g = 0; g < 4; ++g)
                    acc[g] = __builtin_amdgcn_mfma_f32_16x16x32_f16(af[s], wf[g][s], acc[g], 0, 0, 0);
        }

        // K-reduction through LDS: C-tile value (row=quad*4+r -> batch, col=l15 -> jl)
#pragma unroll
        for (int g = 0; g < 4; ++g)
#pragma unroll
            for (int r = 0; r < 4; ++r)
                P[((w * 4 + g) * 16 + quad * 4 + r) * 17 + l15] = acc[g][r];
        __syncthreads();

        float gate[4];
#pragma unroll
        for (int g = 0; g < 4; ++g) {
            float s0 = P[((0 * 4 + g) * 16 + gb) * 17 + gj];
            float s1 = P[((1 * 4 + g) * 16 + gb) * 17 + gj];
            float s2 = P[((2 * 4 + g) * 16 + gb) * 17 + gj];
            float s3 = P[((3 * 4 + g) * 16 + gb) * 17 + gj];
            gate[g] = (s0 + s1) + (s2 + s3);
        }
        __syncthreads();   // protect P reuse next step

        float gi = gate[0] + xgi;
        float gf = gate[1] + xgf;
        float gg = gate[2] + xgg;
        float go = gate[3] + xgo;
        float si = sigf(gi), sf = sigf(gf), so = sigf(go);
        float tg = tanh_fast(gg);
        cst = sf * cst + si * tg;
        float h = so * tanh_fast(cst);

        // publish h: pack f16 pair across adjacent lanes, fire-and-forget sc1 store
        union { f16 f; unsigned short u; } cv; cv.f = (f16)h;
        unsigned hv = cv.u;
        unsigned ov = __shfl_xor(hv, 1);
        if (!(tid & 1))
            __hip_atomic_store(&hw[(((long)t * BATCH + bG) * HID + jG) >> 1],
                               hv | (ov << 16), __ATOMIC_RELAXED, __HIP_MEMORY_SCOPE_AGENT);
        if (out32) out32[((long)bG * SEQ + t) * HID + jG] = h;
    }
}

// ---------------- host ----------------------------------------------------------------
extern "C" void kernel_launch(void* const* d_in, const int* in_sizes, int n_in,
                              void* d_out, int out_size, void* d_ws, size_t ws_size,
                              hipStream_t stream) {
    (void)in_sizes; (void)n_in; (void)out_size; (void)ws_size;
    const float* x    = (const float*)d_in[0];
    const float* Wih0 = (const float*)d_in[1];
    const float* Whh0 = (const float*)d_in[2];
    const float* bih0 = (const float*)d_in[3];
    const float* bhh0 = (const float*)d_in[4];
    const float* Wih1 = (const float*)d_in[5];
    const float* Whh1 = (const float*)d_in[6];
    const float* bih1 = (const float*)d_in[7];
    const float* bhh1 = (const float*)d_in[8];

    char* ws = (char*)d_ws;
    size_t off = 0;
    auto alloc = [&](size_t bytes) { char* p = ws + off; off += (bytes + 255) & ~(size_t)255; return p; };
    f16*   XG   = (f16*)alloc((size_t)SEQ * BATCH * NG * 2);     // 256 MB
    f16*   xh   = (f16*)alloc((size_t)BATCH * SEQ * DPAD * 2);   // 56 MB
    f16*   h1   = (f16*)alloc((size_t)SEQ * BATCH * HID * 2);    // 64 MB (layer-1 h)
    f16*   h2   = (f16*)alloc((size_t)SEQ * BATCH * HID * 2);    // 64 MB (layer-2 h)
    f16*   W0h  = (f16*)alloc((size_t)NG * DPAD * 2);
    f16*   Wh0h = (f16*)alloc((size_t)NG * HID * 2);
    f16*   W1h  = (f16*)alloc((size_t)NG * HID * 2);
    f16*   Wh1h = (f16*)alloc((size_t)NG * HID * 2);
    float* b0   = (float*)alloc((size_t)NG * 4);
    float* b1   = (float*)alloc((size_t)NG * 4);

    prep_kernel<<<dim3(2048), dim3(256), 0, stream>>>(x, Wih0, Whh0, bih0, bhh0,
                                                      Wih1, Whh1, bih1, bhh1,
                                                      xh, W0h, Wh0h, W1h, Wh1h, b0, b1,
                                                      (unsigned*)h1, (unsigned*)h2);

    gemm_f16<<<dim3(8192), dim3(256), 0, stream>>>(xh, W0h, b0, XG, DPAD, 1);

    {
        const f16* xgp = XG; const f16* whp = Wh0h; f16* hp = h1; float* op = nullptr;
        void* args[] = { (void*)&xgp, (void*)&whp, (void*)&hp, (void*)&op };
        (void)hipLaunchCooperativeKernel((const void*)lstm_layer, dim3(256), dim3(256), args, 0, stream);
    }

    gemm_f16<<<dim3(8192), dim3(256), 0, stream>>>(h1, W1h, b1, XG, HID, 2);

    {
        const f16* xgp = XG; const f16* whp = Wh1h; f16* hp = h2; float* op = (float*)d_out;
        void* args[] = { (void*)&xgp, (void*)&whp, (void*)&hp, (void*)&op };
        (void)hipLaunchCooperativeKernel((const void*)lstm_layer, dim3(256), dim3(256), args, 0, stream);
    }
}

// Round 5
// 6265.669 us; speedup vs baseline: 1.0258x; 1.0258x over previous
//
#include <hip/hip_runtime.h>
#include <cstdint>

#define BATCH 64
#define SEQ   512
#define DIN   862
#define DPAD  896
#define HID   1024
#define NG    4096
#define POIS  0xFFFFFFFFu   // f16 NaN pair: |h|<=1 can never produce this pattern

typedef _Float16 f16;
typedef __attribute__((ext_vector_type(8))) _Float16 f16x8;
typedef __attribute__((ext_vector_type(4))) float    f32x4;
typedef unsigned long long u64;

// ---------------- async global->LDS (16B per lane, wave-uniform LDS base) -------------
__device__ __forceinline__ void glds16(const f16* g, f16* l) {
    auto gp = (const __attribute__((address_space(1))) void*)(uintptr_t)g;
    auto lp = (__attribute__((address_space(3))) void*)(uint32_t)(uintptr_t)l;
    __builtin_amdgcn_global_load_lds(gp, lp, 16, 0, 0);
}

__device__ __forceinline__ float sigf(float x) {
    return __builtin_amdgcn_rcpf(1.f + __expf(-x));
}
__device__ __forceinline__ float tanh_fast(float x) {
    float xx = fminf(15.f, fmaxf(-15.f, x));
    float e = __expf(2.f * xx);
    return (e - 1.f) * __builtin_amdgcn_rcpf(e + 1.f);
}

// XG layout: [t][bs(4)][jg(64)][g(4)][bl(16)][jl(16)]  (f16, bias included)
__device__ __forceinline__ long xg_index(int t, int b, int n) {
    int bs = b >> 4, bl = b & 15;
    int g = n >> 10, jh = n & 1023;
    int jg = jh >> 4, jl = jh & 15;
    return (((((long)t * 4 + bs) * 64 + jg) * 4 + g) * 16 + bl) * 16 + jl;
}

// ---- h-fragment loads ----------------------------------------------------------------
// sc0: bypass L1, read the local XCD's L2 (fast path when producer shares the XCD).
__device__ __forceinline__ void load8_sc0(const f16* p, f16x8* af) {
    asm volatile(
        "global_load_dwordx4 %0, %8, off sc0\n\t"
        "global_load_dwordx4 %1, %8, off offset:64 sc0\n\t"
        "global_load_dwordx4 %2, %8, off offset:128 sc0\n\t"
        "global_load_dwordx4 %3, %8, off offset:192 sc0\n\t"
        "global_load_dwordx4 %4, %8, off offset:256 sc0\n\t"
        "global_load_dwordx4 %5, %8, off offset:320 sc0\n\t"
        "global_load_dwordx4 %6, %8, off offset:384 sc0\n\t"
        "global_load_dwordx4 %7, %8, off offset:448 sc0\n\t"
        "s_waitcnt vmcnt(0)"
        : "=&v"(af[0]), "=&v"(af[1]), "=&v"(af[2]), "=&v"(af[3]),
          "=&v"(af[4]), "=&v"(af[5]), "=&v"(af[6]), "=&v"(af[7])
        : "v"(p)
        : "memory");
}
// sc1: IF-coherent — correctness fallback under any block->XCD mapping.
__device__ __forceinline__ void load8_sc1(const f16* p, f16x8* af) {
#pragma unroll
    for (int s = 0; s < 8; ++s) {
        const u64* q = (const u64*)(p + s * 32);
        union { u64 u[2]; f16x8 v; } cv2;
        cv2.u[0] = __hip_atomic_load((u64*)q,     __ATOMIC_RELAXED, __HIP_MEMORY_SCOPE_AGENT);
        cv2.u[1] = __hip_atomic_load((u64*)q + 1, __ATOMIC_RELAXED, __HIP_MEMORY_SCOPE_AGENT);
        af[s] = cv2.v;
    }
}
__device__ __forceinline__ bool frags_ok(const f16x8* af) {
    bool ok = true;
#pragma unroll
    for (int s = 0; s < 8; ++s) {
        union { f16x8 v; unsigned u[4]; } c; c.v = af[s];
#pragma unroll
        for (int q = 0; q < 4; ++q) ok = ok && (c.u[q] != POIS);
    }
    return ok;
}

// ---------------- prep: conversions, padding, bias sums, h-buffer poisoning -----------
__global__ __launch_bounds__(256) void prep_kernel(
    const float* __restrict__ x,
    const float* __restrict__ Wih0, const float* __restrict__ Whh0,
    const float* __restrict__ bih0, const float* __restrict__ bhh0,
    const float* __restrict__ Wih1, const float* __restrict__ Whh1,
    const float* __restrict__ bih1, const float* __restrict__ bhh1,
    f16* __restrict__ xh, f16* __restrict__ W0h, f16* __restrict__ Wh0h,
    f16* __restrict__ W1h, f16* __restrict__ Wh1h,
    float* __restrict__ b0, float* __restrict__ b1,
    unsigned* __restrict__ h1p, unsigned* __restrict__ h2p)
{
    long tid = (long)blockIdx.x * blockDim.x + threadIdx.x;
    long np  = (long)gridDim.x * blockDim.x;
    for (long i = tid; i < (long)BATCH * SEQ * DPAD; i += np) {
        long m = i / DPAD, k = i % DPAD;
        xh[i] = (k < DIN) ? (f16)x[m * DIN + k] : (f16)0.f;
    }
    for (long i = tid; i < (long)NG * DPAD; i += np) {
        long n = i / DPAD, k = i % DPAD;
        W0h[i] = (k < DIN) ? (f16)Wih0[n * DIN + k] : (f16)0.f;
    }
    for (long i = tid; i < (long)NG * HID; i += np) {
        Wh0h[i] = (f16)Whh0[i];
        W1h[i]  = (f16)Wih1[i];
        Wh1h[i] = (f16)Whh1[i];
    }
    for (long i = tid; i < NG; i += np) { b0[i] = bih0[i] + bhh0[i]; b1[i] = bih1[i] + bhh1[i]; }
    // poison both h buffers at the coherence point (sc1 stores)
    const long HW = (long)SEQ * BATCH * HID / 2;   // u32 count
    for (long i = tid; i < HW; i += np) {
        __hip_atomic_store(&h1p[i], POIS, __ATOMIC_RELAXED, __HIP_MEMORY_SCOPE_AGENT);
        __hip_atomic_store(&h2p[i], POIS, __ATOMIC_RELAXED, __HIP_MEMORY_SCOPE_AGENT);
    }
}

// ---------------- f16 GEMM: gates[m][n] = A[m][:K] . Bw[n][:K] + bias[n] --------------
// A [32768][K], Bw [4096][K] (row-major, = W^T applied), out = XG layout (f16).
// mode 1: A rows are m = b*512 + t   (layer-1 input x)
// mode 2: A rows are m = t*64 + b    (layer-2 input h1)
__global__ __launch_bounds__(256) void gemm_f16(
    const f16* __restrict__ A, const f16* __restrict__ Bw,
    const float* __restrict__ bias, f16* __restrict__ out, int K, int mode)
{
    __shared__ f16 smem[2 * 128 * 32];   // A tile | B tile, 8KB each
    const int tid  = threadIdx.x;
    const int lane = tid & 63, wave = tid >> 6;
    const int wm = wave >> 1, wn = wave & 1;
    const int quad = lane >> 4, l15 = lane & 15;
    const int bm = blockIdx.x >> 5, bn = blockIdx.x & 31;
    const long m0 = (long)bm * 128, n0 = (long)bn * 128;
    const int r4 = lane >> 2, g4 = lane & 3;

    f32x4 acc[4][4];
#pragma unroll
    for (int i = 0; i < 4; ++i)
#pragma unroll
        for (int j = 0; j < 4; ++j)
#pragma unroll
            for (int r = 0; r < 4; ++r) acc[i][j][r] = 0.f;

#pragma unroll 1
    for (int kk = 0; kk < K; kk += 32) {
#pragma unroll
        for (int c = 0; c < 2; ++c) {
            int idx = wave * 2 + c;
            int lr  = idx * 16 + r4;
            int gs  = g4 ^ ((lr >> 1) & 3);          // XOR-swizzled source granule
            glds16(A  + (m0 + lr) * (long)K + kk + gs * 8, smem + idx * 512);
            glds16(Bw + (n0 + lr) * (long)K + kk + gs * 8, smem + 4096 + idx * 512);
        }
        __syncthreads();
        f16x8 af[4], bf[4];
#pragma unroll
        for (int i = 0; i < 4; ++i) {
            int lr = 64 * wm + 16 * i + l15;
            int sl = quad ^ ((lr >> 1) & 3);
            af[i] = *(const f16x8*)(smem + lr * 32 + sl * 8);
        }
#pragma unroll
        for (int j = 0; j < 4; ++j) {
            int lr = 64 * wn + 16 * j + l15;
            int sl = quad ^ ((lr >> 1) & 3);
            bf[j] = *(const f16x8*)(smem + 4096 + lr * 32 + sl * 8);
        }
#pragma unroll
        for (int i = 0; i < 4; ++i)
#pragma unroll
            for (int j = 0; j < 4; ++j)
                acc[i][j] = __builtin_amdgcn_mfma_f32_16x16x32_f16(af[i], bf[j], acc[i][j], 0, 0, 0);
        __syncthreads();
    }

#pragma unroll
    for (int j = 0; j < 4; ++j) {
        int n = (int)n0 + 64 * wn + 16 * j + l15;
        float bv = bias[n];
#pragma unroll
        for (int i = 0; i < 4; ++i) {
#pragma unroll
            for (int r = 0; r < 4; ++r) {
                int m = (int)m0 + 64 * wm + 16 * i + quad * 4 + r;
                int t, b;
                if (mode == 1) { b = m >> 9; t = m & 511; }
                else           { t = m >> 6; b = m & 63; }
                out[xg_index(t, b, n)] = (f16)(acc[i][j][r] + bv);
            }
        }
    }
}

// ---------------- persistent LSTM layer, XCD-local data-flow sync ---------------------
// 512 blocks, 2/CU. Group g = blocks with blockIdx&7==g (one XCD under round-robin
// dispatch): 8 batches (g*8..g*8+7) x 64 jg-blocks (16 hidden units each).
// h publish = dual store: normal store (local XCD L2, fast same-XCD visibility) +
// sc1 store (IF, correctness under ANY mapping). Consumers poll with sc0 loads
// (L1-bypass, XCD-L2 coherent); every 8th retry uses sc1 (progress guarantee, G16).
// A-fragment rows duplicate the 8 batches via l15&7 (same-addr loads broadcast).
__global__ __launch_bounds__(256, 2) void lstm_layer_x(
    const f16* __restrict__ xg, const f16* __restrict__ Whh,
    f16* __restrict__ hseq, float* __restrict__ out32)
{
    __shared__ float P[4 * 4 * 16 * 17];   // [src w][g][row 16][j 16+pad]
    const int tid = threadIdx.x;
    const int lane = tid & 63, w = tid >> 6;
    const int quad = lane >> 4, l15 = lane & 15;
    const int grp = blockIdx.x & 7;       // intended XCD / batch group (8 batches)
    const int jg  = blockIdx.x >> 3;      // hidden group: units jg*16..jg*16+15
    const int ks0 = 256 * w;              // this wave's K-slice

    __builtin_amdgcn_fence(__ATOMIC_ACQUIRE, "agent");  // drop stale pre-kernel lines

    // persistent W_hh fragments: wf[gate][kstep]; B-frag row l15 = hidden jl
    f16x8 wf[4][8];
#pragma unroll
    for (int g = 0; g < 4; ++g) {
        const f16* Wp = Whh + ((long)g * HID + jg * 16 + l15) * HID + ks0 + quad * 8;
#pragma unroll
        for (int s = 0; s < 8; ++s)
            wf[g][s] = *(const f16x8*)(Wp + s * 32);
    }
#pragma unroll
    for (int g = 0; g < 4; ++g)
#pragma unroll
        for (int s = 0; s < 8; ++s)
            asm volatile("" : "+v"(wf[g][s]));   // pin: no remat inside t-loop

    // gate-apply assignment (tid<128): b = tid>>4 (0..7), j = tid&15
    const int gb = tid >> 4, gj = tid & 15;
    const int bG = grp * 8 + gb;          // valid for gb<8
    const int jG = jg * 16 + gj;
    unsigned* hw = (unsigned*)hseq;
    float cst = 0.f;

#pragma unroll 1
    for (int t = 0; t < SEQ; ++t) {
        float xgi = 0.f, xgf = 0.f, xgg = 0.f, xgo = 0.f;
        if (tid < 128) {   // xg loads: issue before the poll, hide under it
            int bs = bG >> 4, bl = bG & 15;
            const f16* xp = xg + ((((long)t * 4 + bs) * 64 + jg) * 4) * 256 + bl * 16 + gj;
            xgi = (float)xp[0];
            xgf = (float)xp[256];
            xgg = (float)xp[512];
            xgo = (float)xp[768];
        }

        f32x4 acc[4];
#pragma unroll
        for (int g = 0; g < 4; ++g)
#pragma unroll
            for (int r = 0; r < 4; ++r) acc[g][r] = 0.f;

        if (t > 0) {
            // rows duplicate the 8 batches: row l15 -> batch grp*8 + (l15&7)
            const f16* hpf = hseq + ((long)(t - 1) * BATCH + grp * 8 + (l15 & 7)) * HID
                                  + ks0 + quad * 8;
            f16x8 af[8];
            int it = 0;
            for (;;) {
                if ((it & 7) != 7) load8_sc0(hpf, af);   // XCD-L2 fast path
                else               load8_sc1(hpf, af);   // IF fallback (progress)
                ++it;
                if (__all((int)frags_ok(af))) break;
                __builtin_amdgcn_s_sleep(1);
            }
#pragma unroll
            for (int s = 0; s < 8; ++s)
#pragma unroll
                for (int g = 0; g < 4; ++g)
                    acc[g] = __builtin_amdgcn_mfma_f32_16x16x32_f16(af[s], wf[g][s], acc[g], 0, 0, 0);
        }

        // K-reduction through LDS: C row = quad*4+r (batch, rows 8..15 dup), col = jl
#pragma unroll
        for (int g = 0; g < 4; ++g)
#pragma unroll
            for (int r = 0; r < 4; ++r)
                P[((w * 4 + g) * 16 + quad * 4 + r) * 17 + l15] = acc[g][r];
        __syncthreads();

        float gate[4] = {0.f, 0.f, 0.f, 0.f};
        if (tid < 128) {
#pragma unroll
            for (int g = 0; g < 4; ++g) {
                float s0 = P[((0 * 4 + g) * 16 + gb) * 17 + gj];
                float s1 = P[((1 * 4 + g) * 16 + gb) * 17 + gj];
                float s2 = P[((2 * 4 + g) * 16 + gb) * 17 + gj];
                float s3 = P[((3 * 4 + g) * 16 + gb) * 17 + gj];
                gate[g] = (s0 + s1) + (s2 + s3);
            }
        }
        __syncthreads();   // protect P reuse next step

        if (tid < 128) {
            float gi = gate[0] + xgi;
            float gf = gate[1] + xgf;
            float gg = gate[2] + xgg;
            float go = gate[3] + xgo;
            float si = sigf(gi), sf = sigf(gf), so = sigf(go);
            float tg = tanh_fast(gg);
            cst = sf * cst + si * tg;
            float h = so * tanh_fast(cst);

            // publish h: pack f16 pair across adjacent lanes; dual store
            union { f16 f; unsigned short u; } cv; cv.f = (f16)h;
            unsigned hv = cv.u;
            unsigned ov = __shfl_xor(hv, 1);
            if (!(tid & 1)) {
                unsigned val = hv | (ov << 16);
                unsigned* p = &hw[(((long)t * BATCH + bG) * HID + jG) >> 1];
                __hip_atomic_store(p, val, __ATOMIC_RELAXED, __HIP_MEMORY_SCOPE_WORKGROUP); // local L2
                __hip_atomic_store(p, val, __ATOMIC_RELAXED, __HIP_MEMORY_SCOPE_AGENT);     // IF
            }
            if (out32) out32[((long)bG * SEQ + t) * HID + jG] = h;
        }
    }
}

// ---------------- fallback: round-4 proven 256-block kernel ---------------------------
__global__ __launch_bounds__(256, 1) void lstm_layer(
    const f16* __restrict__ xg, const f16* __restrict__ Whh,
    f16* __restrict__ hseq, float* __restrict__ out32)
{
    __shared__ float P[4 * 4 * 16 * 17];
    const int tid = threadIdx.x;
    const int lane = tid & 63, w = tid >> 6;
    const int quad = lane >> 4, l15 = lane & 15;
    const int bs = blockIdx.x & 3;
    const int jg = blockIdx.x >> 2;
    const int ks0 = 256 * w;

    f16x8 wf[4][8];
#pragma unroll
    for (int g = 0; g < 4; ++g) {
        const f16* Wp = Whh + ((long)g * HID + jg * 16 + l15) * HID + ks0 + quad * 8;
#pragma unroll
        for (int s = 0; s < 8; ++s)
            wf[g][s] = *(const f16x8*)(Wp + s * 32);
    }
#pragma unroll
    for (int g = 0; g < 4; ++g)
#pragma unroll
        for (int s = 0; s < 8; ++s)
            asm volatile("" : "+v"(wf[g][s]));

    const int gb = tid >> 4, gj = tid & 15;
    const int bG = bs * 16 + gb, jG = jg * 16 + gj;
    unsigned* hw = (unsigned*)hseq;
    float cst = 0.f;

#pragma unroll 1
    for (int t = 0; t < SEQ; ++t) {
        const f16* xp = xg + (((long)t * 4 + bs) * 64 + jg) * 1024 + gb * 16 + gj;
        float xgi = (float)xp[0];
        float xgf = (float)xp[256];
        float xgg = (float)xp[512];
        float xgo = (float)xp[768];

        f32x4 acc[4];
#pragma unroll
        for (int g = 0; g < 4; ++g)
#pragma unroll
            for (int r = 0; r < 4; ++r) acc[g][r] = 0.f;

        if (t > 0) {
            const f16* hpf = hseq + ((long)(t - 1) * BATCH + bs * 16 + l15) * HID + ks0 + quad * 8;
            f16x8 af[8];
            for (;;) {
                load8_sc1(hpf, af);
                if (__all((int)frags_ok(af))) break;
                __builtin_amdgcn_s_sleep(1);
            }
#pragma unroll
            for (int s = 0; s < 8; ++s)
#pragma unroll
                for (int g = 0; g < 4; ++g)
                    acc[g] = __builtin_amdgcn_mfma_f32_16x16x32_f16(af[s], wf[g][s], acc[g], 0, 0, 0);
        }

#pragma unroll
        for (int g = 0; g < 4; ++g)
#pragma unroll
            for (int r = 0; r < 4; ++r)
                P[((w * 4 + g) * 16 + quad * 4 + r) * 17 + l15] = acc[g][r];
        __syncthreads();

        float gate[4];
#pragma unroll
        for (int g = 0; g < 4; ++g) {
            float s0 = P[((0 * 4 + g) * 16 + gb) * 17 + gj];
            float s1 = P[((1 * 4 + g) * 16 + gb) * 17 + gj];
            float s2 = P[((2 * 4 + g) * 16 + gb) * 17 + gj];
            float s3 = P[((3 * 4 + g) * 16 + gb) * 17 + gj];
            gate[g] = (s0 + s1) + (s2 + s3);
        }
        __syncthreads();

        float gi = gate[0] + xgi;
        float gf = gate[1] + xgf;
        float gg = gate[2] + xgg;
        float go = gate[3] + xgo;
        float si = sigf(gi), sf = sigf(gf), so = sigf(go);
        float tg = tanh_fast(gg);
        cst = sf * cst + si * tg;
        float h = so * tanh_fast(cst);

        union { f16 f; unsigned short u; } cv; cv.f = (f16)h;
        unsigned hv = cv.u;
        unsigned ov = __shfl_xor(hv, 1);
        if (!(tid & 1))
            __hip_atomic_store(&hw[(((long)t * BATCH + bG) * HID + jG) >> 1],
                               hv | (ov << 16), __ATOMIC_RELAXED, __HIP_MEMORY_SCOPE_AGENT);
        if (out32) out32[((long)bG * SEQ + t) * HID + jG] = h;
    }
}

// ---------------- host ----------------------------------------------------------------
extern "C" void kernel_launch(void* const* d_in, const int* in_sizes, int n_in,
                              void* d_out, int out_size, void* d_ws, size_t ws_size,
                              hipStream_t stream) {
    (void)in_sizes; (void)n_in; (void)out_size; (void)ws_size;
    const float* x    = (const float*)d_in[0];
    const float* Wih0 = (const float*)d_in[1];
    const float* Whh0 = (const float*)d_in[2];
    const float* bih0 = (const float*)d_in[3];
    const float* bhh0 = (const float*)d_in[4];
    const float* Wih1 = (const float*)d_in[5];
    const float* Whh1 = (const float*)d_in[6];
    const float* bih1 = (const float*)d_in[7];
    const float* bhh1 = (const float*)d_in[8];

    char* ws = (char*)d_ws;
    size_t off = 0;
    auto alloc = [&](size_t bytes) { char* p = ws + off; off += (bytes + 255) & ~(size_t)255; return p; };
    f16*   XG   = (f16*)alloc((size_t)SEQ * BATCH * NG * 2);     // 256 MB
    f16*   xh   = (f16*)alloc((size_t)BATCH * SEQ * DPAD * 2);   // 56 MB
    f16*   h1   = (f16*)alloc((size_t)SEQ * BATCH * HID * 2);    // 64 MB (layer-1 h)
    f16*   h2   = (f16*)alloc((size_t)SEQ * BATCH * HID * 2);    // 64 MB (layer-2 h)
    f16*   W0h  = (f16*)alloc((size_t)NG * DPAD * 2);
    f16*   Wh0h = (f16*)alloc((size_t)NG * HID * 2);
    f16*   W1h  = (f16*)alloc((size_t)NG * HID * 2);
    f16*   Wh1h = (f16*)alloc((size_t)NG * HID * 2);
    float* b0   = (float*)alloc((size_t)NG * 4);
    float* b1   = (float*)alloc((size_t)NG * 4);

    prep_kernel<<<dim3(2048), dim3(256), 0, stream>>>(x, Wih0, Whh0, bih0, bhh0,
                                                      Wih1, Whh1, bih1, bhh1,
                                                      xh, W0h, Wh0h, W1h, Wh1h, b0, b1,
                                                      (unsigned*)h1, (unsigned*)h2);

    gemm_f16<<<dim3(8192), dim3(256), 0, stream>>>(xh, W0h, b0, XG, DPAD, 1);

    int occ = 0;
    (void)hipOccupancyMaxActiveBlocksPerMultiprocessor(&occ, (const void*)lstm_layer_x, 256, 0);
    const bool use_x = (occ >= 2);

    {
        const f16* xgp = XG; const f16* whp = Wh0h; f16* hp = h1; float* op = nullptr;
        void* args[] = { (void*)&xgp, (void*)&whp, (void*)&hp, (void*)&op };
        if (use_x)
            (void)hipLaunchCooperativeKernel((const void*)lstm_layer_x, dim3(512), dim3(256), args, 0, stream);
        else
            (void)hipLaunchCooperativeKernel((const void*)lstm_layer, dim3(256), dim3(256), args, 0, stream);
    }

    gemm_f16<<<dim3(8192), dim3(256), 0, stream>>>(h1, W1h, b1, XG, HID, 2);

    {
        const f16* xgp = XG; const f16* whp = Wh1h; f16* hp = h2; float* op = (float*)d_out;
        void* args[] = { (void*)&xgp, (void*)&whp, (void*)&hp, (void*)&op };
        if (use_x)
            (void)hipLaunchCooperativeKernel((const void*)lstm_layer_x, dim3(512), dim3(256), args, 0, stream);
        else
            (void)hipLaunchCooperativeKernel((const void*)lstm_layer, dim3(256), dim3(256), args, 0, stream);
    }
}

// Round 6
// 6098.806 us; speedup vs baseline: 1.0539x; 1.0274x over previous
//
#include <hip/hip_runtime.h>
#include <cstdint>

#define BATCH 64
#define SEQ   512
#define DIN   862
#define DPAD  896
#define HID   1024
#define NG    4096

typedef _Float16 f16;
typedef __attribute__((ext_vector_type(8))) _Float16 f16x8;
typedef __attribute__((ext_vector_type(4))) float    f32x4;
typedef unsigned long long u64;

// ---------------- async global->LDS (16B per lane, wave-uniform LDS base) -------------
__device__ __forceinline__ void glds16(const f16* g, f16* l) {
    auto gp = (const __attribute__((address_space(1))) void*)(uintptr_t)g;
    auto lp = (__attribute__((address_space(3))) void*)(uint32_t)(uintptr_t)l;
    __builtin_amdgcn_global_load_lds(gp, lp, 16, 0, 0);
}

__device__ __forceinline__ float sigf(float x) {
    return __builtin_amdgcn_rcpf(1.f + __expf(-x));
}
__device__ __forceinline__ float tanh_fast(float x) {
    float xx = fminf(15.f, fmaxf(-15.f, x));
    float e = __expf(2.f * xx);
    return (e - 1.f) * __builtin_amdgcn_rcpf(e + 1.f);
}

// XG layout: [t][bs(4)][jg(64)][g(4)][bl(16)][jl(16)]  (f16, bias included)
__device__ __forceinline__ long xg_index(int t, int b, int n) {
    int bs = b >> 4, bl = b & 15;
    int g = n >> 10, jh = n & 1023;
    int jg = jh >> 4, jl = jh & 15;
    return (((((long)t * 4 + bs) * 64 + jg) * 4 + g) * 16 + bl) * 16 + jl;
}

// coherent (L2-bypassing) h-fragment load: 8 x 16B, per-s stride 32 f16 = 64 B
__device__ __forceinline__ f16x8 h_frag_load(const f16* p) {
    union { u64 u[2]; f16x8 v; } r;
    r.u[0] = __hip_atomic_load((u64*)p,     __ATOMIC_RELAXED, __HIP_MEMORY_SCOPE_AGENT);
    r.u[1] = __hip_atomic_load((u64*)p + 1, __ATOMIC_RELAXED, __HIP_MEMORY_SCOPE_AGENT);
    return r.v;
}

// ---------------- prep: fp32->fp16 conversions, padding, bias sums, barrier zero ------
__global__ __launch_bounds__(256) void prep_kernel(
    const float* __restrict__ x,
    const float* __restrict__ Wih0, const float* __restrict__ Whh0,
    const float* __restrict__ bih0, const float* __restrict__ bhh0,
    const float* __restrict__ Wih1, const float* __restrict__ Whh1,
    const float* __restrict__ bih1, const float* __restrict__ bhh1,
    f16* __restrict__ xh, f16* __restrict__ W0h, f16* __restrict__ Wh0h,
    f16* __restrict__ W1h, f16* __restrict__ Wh1h,
    float* __restrict__ b0, float* __restrict__ b1, unsigned* __restrict__ bar)
{
    long tid = (long)blockIdx.x * blockDim.x + threadIdx.x;
    long np  = (long)gridDim.x * blockDim.x;
    for (long i = tid; i < (long)BATCH * SEQ * DPAD; i += np) {
        long m = i / DPAD, k = i % DPAD;
        xh[i] = (k < DIN) ? (f16)x[m * DIN + k] : (f16)0.f;
    }
    for (long i = tid; i < (long)NG * DPAD; i += np) {
        long n = i / DPAD, k = i % DPAD;
        W0h[i] = (k < DIN) ? (f16)Wih0[n * DIN + k] : (f16)0.f;
    }
    for (long i = tid; i < (long)NG * HID; i += np) {
        Wh0h[i] = (f16)Whh0[i];
        W1h[i]  = (f16)Wih1[i];
        Wh1h[i] = (f16)Whh1[i];
    }
    for (long i = tid; i < NG; i += np) { b0[i] = bih0[i] + bhh0[i]; b1[i] = bih1[i] + bhh1[i]; }
    for (long i = tid; i < 2048; i += np) bar[i] = 0u;
}

// ---------------- f16 GEMM: gates[m][n] = A[m][:K] . Bw[n][:K] + bias[n] --------------
// A [32768][K], Bw [4096][K] (row-major, = W^T applied), out = XG layout (f16).
// mode 1: A rows are m = b*512 + t   (layer-1 input x)
// mode 2: A rows are m = t*64 + b    (layer-2 input h1)
__global__ __launch_bounds__(256) void gemm_f16(
    const f16* __restrict__ A, const f16* __restrict__ Bw,
    const float* __restrict__ bias, f16* __restrict__ out, int K, int mode)
{
    __shared__ f16 smem[2 * 128 * 32];   // A tile | B tile, 8KB each
    const int tid  = threadIdx.x;
    const int lane = tid & 63, wave = tid >> 6;
    const int wm = wave >> 1, wn = wave & 1;
    const int quad = lane >> 4, l15 = lane & 15;
    const int bm = blockIdx.x >> 5, bn = blockIdx.x & 31;
    const long m0 = (long)bm * 128, n0 = (long)bn * 128;
    const int r4 = lane >> 2, g4 = lane & 3;

    f32x4 acc[4][4];
#pragma unroll
    for (int i = 0; i < 4; ++i)
#pragma unroll
        for (int j = 0; j < 4; ++j)
#pragma unroll
            for (int r = 0; r < 4; ++r) acc[i][j][r] = 0.f;

#pragma unroll 1
    for (int kk = 0; kk < K; kk += 32) {
#pragma unroll
        for (int c = 0; c < 2; ++c) {
            int idx = wave * 2 + c;
            int lr  = idx * 16 + r4;
            int gs  = g4 ^ ((lr >> 1) & 3);          // XOR-swizzled source granule
            glds16(A  + (m0 + lr) * (long)K + kk + gs * 8, smem + idx * 512);
            glds16(Bw + (n0 + lr) * (long)K + kk + gs * 8, smem + 4096 + idx * 512);
        }
        __syncthreads();
        f16x8 af[4], bf[4];
#pragma unroll
        for (int i = 0; i < 4; ++i) {
            int lr = 64 * wm + 16 * i + l15;
            int sl = quad ^ ((lr >> 1) & 3);
            af[i] = *(const f16x8*)(smem + lr * 32 + sl * 8);
        }
#pragma unroll
        for (int j = 0; j < 4; ++j) {
            int lr = 64 * wn + 16 * j + l15;
            int sl = quad ^ ((lr >> 1) & 3);
            bf[j] = *(const f16x8*)(smem + 4096 + lr * 32 + sl * 8);
        }
#pragma unroll
        for (int i = 0; i < 4; ++i)
#pragma unroll
            for (int j = 0; j < 4; ++j)
                acc[i][j] = __builtin_amdgcn_mfma_f32_16x16x32_f16(af[i], bf[j], acc[i][j], 0, 0, 0);
        __syncthreads();
    }

#pragma unroll
    for (int j = 0; j < 4; ++j) {
        int n = (int)n0 + 64 * wn + 16 * j + l15;
        float bv = bias[n];
#pragma unroll
        for (int i = 0; i < 4; ++i) {
#pragma unroll
            for (int r = 0; r < 4; ++r) {
                int m = (int)m0 + 64 * wm + 16 * i + quad * 4 + r;
                int t, b;
                if (mode == 1) { b = m >> 9; t = m & 511; }
                else           { t = m >> 6; b = m & 63; }
                out[xg_index(t, b, n)] = (f16)(acc[i][j][r] + bv);
            }
        }
    }
}

// ---------------- fence-free grid barrier ---------------------------------------------
// Cross-block data (h) moves via sc1 (agent-scope) atomics, so no L2 writeback/inv is
// needed. s_waitcnt vmcnt(0) by every thread drains write-through stores first.
__device__ __forceinline__ void grid_barrier_nf(unsigned* bar, unsigned target) {
    asm volatile("s_waitcnt vmcnt(0)" ::: "memory");
    __syncthreads();
    if (threadIdx.x == 0) {
        unsigned grp = blockIdx.x >> 4;
        unsigned prev = __hip_atomic_fetch_add(&bar[grp * 32], 1u, __ATOMIC_RELAXED, __HIP_MEMORY_SCOPE_AGENT);
        if ((prev & 15u) == 15u) {
            unsigned pr = __hip_atomic_fetch_add(&bar[512], 1u, __ATOMIC_RELAXED, __HIP_MEMORY_SCOPE_AGENT);
            if ((pr & 15u) == 15u)
                __hip_atomic_store(&bar[544], target, __ATOMIC_RELAXED, __HIP_MEMORY_SCOPE_AGENT);
        }
        while (__hip_atomic_load(&bar[544], __ATOMIC_RELAXED, __HIP_MEMORY_SCOPE_AGENT) < target)
            __builtin_amdgcn_s_sleep(1);
    }
    __syncthreads();
}

// ---------------- persistent LSTM layer -----------------------------------------------
// 256 blocks = 4 batch-slices x 64 hidden-groups; 1 block/CU, 1 wave/SIMD.
// amdgpu_waves_per_eu(1,1): occupancy target = 1 -> allocator may use the full 512-VGPR
// budget, so the 128-VGPR W_hh fragment set stays RESIDENT (prior rounds: VGPR=88-104,
// i.e. wf spilled to scratch and re-read every step on the critical path).
// The in-loop empty-asm pin makes wf a loop-carried register dependency: remat from
// memory is semantically forbidden at every iteration boundary.
__global__ __launch_bounds__(256, 1) __attribute__((amdgpu_waves_per_eu(1, 1)))
void lstm_layer(
    const f16* __restrict__ xg, const f16* __restrict__ Whh,
    f16* __restrict__ hseq, float* __restrict__ out32, unsigned* __restrict__ bar)
{
    __shared__ float P[4 * 4 * 16 * 17];   // [src w][g][b 16][j 16+pad] = 17408 B
    const int tid = threadIdx.x;
    const int lane = tid & 63, w = tid >> 6;
    const int quad = lane >> 4, l15 = lane & 15;
    const int bs = blockIdx.x & 3;        // batch slice: batches bs*16..bs*16+15
    const int jg = blockIdx.x >> 2;       // hidden group: units jg*16..jg*16+15
    const int ks0 = 256 * w;              // this wave's K-slice

    // persistent W_hh fragments: wf[gate][kstep]; B-frag row l15 = hidden jl
    f16x8 wf[4][8];
#pragma unroll
    for (int g = 0; g < 4; ++g) {
        const f16* Wp = Whh + ((long)g * HID + jg * 16 + l15) * HID + ks0 + quad * 8;
#pragma unroll
        for (int s = 0; s < 8; ++s)
            wf[g][s] = *(const f16x8*)(Wp + s * 32);
    }

    const int gb = tid >> 4, gj = tid & 15;
    const int bG = bs * 16 + gb, jG = jg * 16 + gj;
    unsigned* hw = (unsigned*)hseq;
    float cst = 0.f;

#pragma unroll 1
    for (int t = 0; t < SEQ; ++t) {
        // pin wf as loop-carried registers: forbids spill-free remat, forces residency
#pragma unroll
        for (int g = 0; g < 4; ++g)
#pragma unroll
            for (int s = 0; s < 8; ++s)
                asm volatile("" : "+v"(wf[g][s]));

        // xg loads: independent of h, issue first so latency hides under MFMA phase
        const f16* xp = xg + (((long)t * 4 + bs) * 64 + jg) * 1024 + gb * 16 + gj;
        float xgi = (float)xp[0];
        float xgf = (float)xp[256];
        float xgg = (float)xp[512];
        float xgo = (float)xp[768];

        f32x4 acc[4];
#pragma unroll
        for (int g = 0; g < 4; ++g)
#pragma unroll
            for (int r = 0; r < 4; ++r) acc[g][r] = 0.f;

        if (t > 0) {
            const f16* hpf = hseq + ((long)(t - 1) * BATCH + bs * 16 + l15) * HID + ks0 + quad * 8;
#pragma unroll
            for (int s = 0; s < 8; ++s) {
                f16x8 af = h_frag_load(hpf + s * 32);
#pragma unroll
                for (int g = 0; g < 4; ++g)
                    acc[g] = __builtin_amdgcn_mfma_f32_16x16x32_f16(af, wf[g][s], acc[g], 0, 0, 0);
            }
        }

        // K-reduction through LDS: C-tile value (row=quad*4+r -> batch, col=l15 -> jl)
#pragma unroll
        for (int g = 0; g < 4; ++g)
#pragma unroll
            for (int r = 0; r < 4; ++r)
                P[((w * 4 + g) * 16 + quad * 4 + r) * 17 + l15] = acc[g][r];
        __syncthreads();

        float gate[4];
#pragma unroll
        for (int g = 0; g < 4; ++g) {
            float s0 = P[((0 * 4 + g) * 16 + gb) * 17 + gj];
            float s1 = P[((1 * 4 + g) * 16 + gb) * 17 + gj];
            float s2 = P[((2 * 4 + g) * 16 + gb) * 17 + gj];
            float s3 = P[((3 * 4 + g) * 16 + gb) * 17 + gj];
            gate[g] = (s0 + s1) + (s2 + s3);
        }

        float gi = gate[0] + xgi;
        float gf = gate[1] + xgf;
        float gg = gate[2] + xgg;
        float go = gate[3] + xgo;
        float si = sigf(gi), sf = sigf(gf), so = sigf(go);
        float tg = tanh_fast(gg);
        cst = sf * cst + si * tg;
        float h = so * tanh_fast(cst);

        // publish h: pack f16 pair across adjacent lanes, write-through sc1 store
        union { f16 f; unsigned short u; } cv; cv.f = (f16)h;
        unsigned hv = cv.u;
        unsigned ov = __shfl_xor(hv, 1);
        if (!(tid & 1))
            __hip_atomic_store(&hw[(((long)t * BATCH + bG) * HID + jG) >> 1],
                               hv | (ov << 16), __ATOMIC_RELAXED, __HIP_MEMORY_SCOPE_AGENT);
        if (out32) out32[((long)bG * SEQ + t) * HID + jG] = h;

        if (t + 1 < SEQ) grid_barrier_nf(bar, (unsigned)(t + 1));
    }
}

// ---------------- host ----------------------------------------------------------------
extern "C" void kernel_launch(void* const* d_in, const int* in_sizes, int n_in,
                              void* d_out, int out_size, void* d_ws, size_t ws_size,
                              hipStream_t stream) {
    (void)in_sizes; (void)n_in; (void)out_size; (void)ws_size;
    const float* x    = (const float*)d_in[0];
    const float* Wih0 = (const float*)d_in[1];
    const float* Whh0 = (const float*)d_in[2];
    const float* bih0 = (const float*)d_in[3];
    const float* bhh0 = (const float*)d_in[4];
    const float* Wih1 = (const float*)d_in[5];
    const float* Whh1 = (const float*)d_in[6];
    const float* bih1 = (const float*)d_in[7];
    const float* bhh1 = (const float*)d_in[8];

    char* ws = (char*)d_ws;
    size_t off = 0;
    auto alloc = [&](size_t bytes) { char* p = ws + off; off += (bytes + 255) & ~(size_t)255; return p; };
    f16*   XG   = (f16*)alloc((size_t)SEQ * BATCH * NG * 2);     // 256 MB
    f16*   xh   = (f16*)alloc((size_t)BATCH * SEQ * DPAD * 2);   // 56 MB
    f16*   h1   = (f16*)alloc((size_t)SEQ * BATCH * HID * 2);    // 64 MB
    f16*   W0h  = (f16*)alloc((size_t)NG * DPAD * 2);
    f16*   Wh0h = (f16*)alloc((size_t)NG * HID * 2);
    f16*   W1h  = (f16*)alloc((size_t)NG * HID * 2);
    f16*   Wh1h = (f16*)alloc((size_t)NG * HID * 2);
    float* b0   = (float*)alloc((size_t)NG * 4);
    float* b1   = (float*)alloc((size_t)NG * 4);
    unsigned* bar = (unsigned*)alloc(2048 * 4);

    prep_kernel<<<dim3(2048), dim3(256), 0, stream>>>(x, Wih0, Whh0, bih0, bhh0,
                                                      Wih1, Whh1, bih1, bhh1,
                                                      xh, W0h, Wh0h, W1h, Wh1h, b0, b1, bar);

    gemm_f16<<<dim3(8192), dim3(256), 0, stream>>>(xh, W0h, b0, XG, DPAD, 1);

    {
        const f16* xgp = XG; const f16* whp = Wh0h; f16* hp = h1;
        float* op = nullptr; unsigned* bp = bar;
        void* args[] = { (void*)&xgp, (void*)&whp, (void*)&hp, (void*)&op, (void*)&bp };
        (void)hipLaunchCooperativeKernel((const void*)lstm_layer, dim3(256), dim3(256), args, 0, stream);
    }

    gemm_f16<<<dim3(8192), dim3(256), 0, stream>>>(h1, W1h, b1, XG, HID, 2);

    {
        const f16* xgp = XG; const f16* whp = Wh1h; f16* hp = h1;
        float* op = (float*)d_out; unsigned* bp = bar + 1024;
        void* args[] = { (void*)&xgp, (void*)&whp, (void*)&hp, (void*)&op, (void*)&bp };
        (void)hipLaunchCooperativeKernel((const void*)lstm_layer, dim3(256), dim3(256), args, 0, stream);
    }
}